// Round 2
// baseline (354.448 us; speedup 1.0000x reference)
//
#include <hip/hip_runtime.h>
#include <stdint.h>

// One wave (64 lanes) per batch row. B=16384 rows, T=4096 int32 each.
// Phase 1: coalesced dword loads + __ballot -> 64-bit yawning mask per
//          64-element chunk; chunk k's mask lands on lane k via predicated
//          move (ballot result is wave-uniform SGPR pair -> v_cndmask).
// Phase 2: per-lane bit-trick summary of its 64-element segment.
// Phase 3: shfl_down tree merge of segment summaries (run-length monoid).
// Phase 4: lane 0 applies exp-decay adjustment + clip, one store per row.

#define NROWS 16384
#define TLEN  4096

__global__ __launch_bounds__(256, 4) void yawn_adjust_kernel(
    const float* __restrict__ drows,
    const int* __restrict__ gest,
    float* __restrict__ out)
{
    const int lane = threadIdx.x & 63;
    const int row  = blockIdx.x * 4 + (threadIdx.x >> 6);
    if (row >= NROWS) return;

    const int* gp = gest + (size_t)row * TLEN + lane;

    // ---- Phase 1: build masks. Lane k ends up holding the 64-bit mask of
    // chunk k (bit i = element k*64+i, LSB = earliest element).
    uint32_t mlo = 0u, mhi = 0u;
    #pragma unroll
    for (int j0 = 0; j0 < 64; j0 += 16) {
        int v[16];
        #pragma unroll
        for (int k = 0; k < 16; ++k)
            v[k] = gp[(j0 + k) * 64];           // coalesced: 256B per wave-load
        #pragma unroll
        for (int k = 0; k < 16; ++k) {
            unsigned long long b = __ballot(v[k] == 2);
            if (lane == j0 + k) {               // predicated move, no branch
                mlo = (uint32_t)b;
                mhi = (uint32_t)(b >> 32);
            }
        }
    }

    // ---- Phase 2: leaf summary of this lane's 64-element segment.
    uint64_t m  = ((uint64_t)mhi << 32) | (uint64_t)mlo;
    bool     full = (m == ~0ull);
    uint64_t nm = ~m;
    int lead  = full ? 64 : (int)__builtin_ctzll(nm);  // run touching segment start
    int trail = full ? 64 : (int)__builtin_clzll(nm);  // run touching segment end

    // interior mask: clear boundary runs (shift amounts forced <64 / mi=0 when full)
    int leadc  = full ? 0 : lead;
    int trailc = full ? 0 : trail;
    uint64_t mi = full ? 0ull : m;
    mi = (mi >> leadc) << leadc;
    mi = (mi << trailc) >> trailc;

    // runs >= 4: w bit i <=> m[i..i+3] all set
    uint64_t w = mi & (mi >> 1);
    w &= (w >> 2);
    int ch = __builtin_popcountll(w & ~(w << 1));   // count of run-starts
    // runs >= 7: w7 bit i <=> m[i..i+6] all set
    uint64_t w7 = w & (w >> 3);
    int cl = __builtin_popcountll(w7 & ~(w7 << 1));

    // ---- Phase 3: tree merge across 64 lanes. After step with offset=off,
    // lane i (i % (2*off) == 0) holds summary of segment [i*64, (i+2*off)*64).
    #pragma unroll
    for (int off = 1, len = 64; off < 64; off <<= 1, len <<= 1) {
        int bch    = __shfl_down(ch,    (unsigned)off, 64);
        int bcl    = __shfl_down(cl,    (unsigned)off, 64);
        int blead  = __shfl_down(lead,  (unsigned)off, 64);
        int btrail = __shfl_down(trail, (unsigned)off, 64);

        bool afull = (lead  == len);
        bool bfull = (blead == len);
        int junction = trail + blead;              // run spanning the seam
        bool interior = (!afull) && (!bfull);
        ch += bch + ((interior && junction >= 4) ? 1 : 0);
        cl += bcl + ((interior && junction >= 7) ? 1 : 0);
        lead  = afull ? (len + blead)  : lead;
        trail = bfull ? (len + trail)  : btrail;
    }

    // ---- Phase 4: finalize + epilogue (lane 0 only).
    if (lane == 0) {
        int hc, lc;
        if (lead == TLEN) {            // entire row is one run
            hc = 1; lc = 1;
        } else {
            hc = ch + (lead >= 4 ? 1 : 0) + (trail >= 4 ? 1 : 0);
            lc = cl + (lead >= 7 ? 1 : 0) + (trail >= 7 ? 1 : 0);
        }
        float hadj = (hc >= 2) ? 0.18f * expf(-0.5f * (float)(hc - 2)) : 0.0f;
        float ladj = (lc >= 3) ? 0.05f * expf(-0.5f * (float)(lc - 3)) : 0.0f;
        float tot  = fminf(hadj + ladj, 0.35f);
        float r    = drows[row] + tot;
        out[row]   = fminf(fmaxf(r, 0.0f), 1.0f);
    }
}

extern "C" void kernel_launch(void* const* d_in, const int* in_sizes, int n_in,
                              void* d_out, int out_size, void* d_ws, size_t ws_size,
                              hipStream_t stream) {
    (void)in_sizes; (void)n_in; (void)d_ws; (void)ws_size; (void)out_size;
    const float* drows = (const float*)d_in[0];
    const int*   gest  = (const int*)d_in[1];
    float*       out   = (float*)d_out;
    dim3 grid(NROWS / 4);   // 4 waves per 256-thread block, one row per wave
    yawn_adjust_kernel<<<grid, 256, 0, stream>>>(drows, gest, out);
}